// Round 1
// baseline (69.782 us; speedup 1.0000x reference)
//
#include <hip/hip_runtime.h>
#include <math.h>

// Problem constants (from reference): B=64, S=512, H=1024
#define BB 64
#define SS 512
#define HH 1024
#define K3 (3 * HH)   // 3072

// Kernel 1: build feats[b, 0:3H] = [ hidden[b,0,:], mean(subj range), mean(obj range) ]
// One block per batch, 256 threads, each thread owns 4 consecutive H-elements (float4).
__global__ __launch_bounds__(256) void feats_kernel(
    const float* __restrict__ hs,     // (B,S,H)
    const int*   __restrict__ subj,   // (B,2)
    const int*   __restrict__ obj,    // (B,2)
    float*       __restrict__ feats)  // (B,3H)
{
    const int b = blockIdx.x;
    const int t = threadIdx.x;                      // 0..255, float4 index within H
    const float4* base = (const float4*)(hs + (size_t)b * SS * HH);
    float4* fout = (float4*)(feats + (size_t)b * K3);

    // first token
    fout[t] = base[t];

    // subj mean
    {
        const int s0 = subj[2 * b], s1 = subj[2 * b + 1];
        float4 acc = make_float4(0.f, 0.f, 0.f, 0.f);
        for (int s = s0; s < s1; ++s) {
            float4 v = base[(size_t)s * (HH / 4) + t];
            acc.x += v.x; acc.y += v.y; acc.z += v.z; acc.w += v.w;
        }
        const float inv = 1.0f / fmaxf((float)(s1 - s0), 1.0f);
        acc.x *= inv; acc.y *= inv; acc.z *= inv; acc.w *= inv;
        fout[(HH / 4) + t] = acc;
    }

    // obj mean
    {
        const int s0 = obj[2 * b], s1 = obj[2 * b + 1];
        float4 acc = make_float4(0.f, 0.f, 0.f, 0.f);
        for (int s = s0; s < s1; ++s) {
            float4 v = base[(size_t)s * (HH / 4) + t];
            acc.x += v.x; acc.y += v.y; acc.z += v.z; acc.w += v.w;
        }
        const float inv = 1.0f / fmaxf((float)(s1 - s0), 1.0f);
        acc.x *= inv; acc.y *= inv; acc.z *= inv; acc.w *= inv;
        fout[2 * (HH / 4) + t] = acc;
    }
}

// Kernel 2: out[b,j] = tanh( dot(feats[b,:], W[j,:]) + bias[j] )
// One wave (64 lanes) per output element. Block = 256 threads = 4 waves:
//   j   = blockIdx.x >> 4           (all 4 waves in a block share the same W row -> L1 broadcast)
//   b   = ((blockIdx.x & 15) << 2) + waveId
// 16 consecutive blocks cover all 64 batches for one j (W row stays L2-hot).
__global__ __launch_bounds__(256) void gemm_tanh_kernel(
    const float* __restrict__ feats,  // (B,3H)
    const float* __restrict__ W,      // (H,3H) row-major
    const float* __restrict__ bias,   // (H)
    float*       __restrict__ out)    // (B,H)
{
    const int wave = threadIdx.x >> 6;
    const int lane = threadIdx.x & 63;
    const int j = blockIdx.x >> 4;
    const int b = ((blockIdx.x & 15) << 2) + wave;

    const float4* fr = (const float4*)(feats + (size_t)b * K3);
    const float4* wr = (const float4*)(W + (size_t)j * K3);

    float acc = 0.f;
#pragma unroll
    for (int i = 0; i < K3 / (4 * 64); ++i) {        // 12 iterations
        const float4 a = fr[i * 64 + lane];
        const float4 w = wr[i * 64 + lane];
        acc += a.x * w.x + a.y * w.y + a.z * w.z + a.w * w.w;
    }

    // wave-wide sum (64 lanes)
#pragma unroll
    for (int off = 32; off > 0; off >>= 1)
        acc += __shfl_xor(acc, off);

    if (lane == 0)
        out[(size_t)b * HH + j] = tanhf(acc + bias[j]);
}

extern "C" void kernel_launch(void* const* d_in, const int* in_sizes, int n_in,
                              void* d_out, int out_size, void* d_ws, size_t ws_size,
                              hipStream_t stream) {
    const float* hs   = (const float*)d_in[0];  // (B,S,H) fp32
    const int*   subj = (const int*)d_in[1];    // (B,2) int32
    const int*   obj  = (const int*)d_in[2];    // (B,2) int32
    const float* W    = (const float*)d_in[3];  // (H,3H) fp32
    const float* bias = (const float*)d_in[4];  // (H) fp32
    float*       out  = (float*)d_out;          // (B,H) fp32

    float* feats = (float*)d_ws;                // needs B*3H*4 = 786,432 bytes

    feats_kernel<<<BB, 256, 0, stream>>>(hs, subj, obj, feats);
    gemm_tanh_kernel<<<(BB / 4) * HH, 256, 0, stream>>>(feats, W, bias, out);
}

// Round 2
// 36.222 us; speedup vs baseline: 1.9265x; 1.9265x over previous
//
#include <hip/hip_runtime.h>
#include <math.h>

// B=64, S=512, H=1024
#define BB 64
#define SS 512
#define HH 1024
#define K3 3072
#define KSPLIT 16
#define KCHUNK 192          // K3 / KSPLIT
#define JTILE 32            // j-columns per block (4 waves x RJ)
#define RJ 8                // j-columns per wave
#define LDS_PAD 196         // row stride in floats: 16B-aligned, bank-balanced

// ---------------- Kernel 1: feats[b, 0:3H] = [first, subj-mean, obj-mean] ----
// grid 256 = (64 b) x (4 h-chunks), 64 threads; thread owns one float4 of H.
__global__ __launch_bounds__(64) void feats_kernel(
    const float* __restrict__ hs,     // (B,S,H)
    const int*   __restrict__ subj,   // (B,2)
    const int*   __restrict__ obj,    // (B,2)
    float*       __restrict__ feats)  // (B,3H) row-major
{
    const int b  = blockIdx.x >> 2;
    const int hc = blockIdx.x & 3;
    const int t  = (hc << 6) + threadIdx.x;          // float4 index in [0,256)
    const float4* base = (const float4*)(hs + (size_t)b * SS * HH);
    float4* fout = (float4*)(feats + (size_t)b * K3);

    // first token
    fout[t] = base[t];

    // subj mean
    {
        const int s0 = subj[2 * b], s1 = subj[2 * b + 1];
        float4 acc = make_float4(0.f, 0.f, 0.f, 0.f);
        #pragma unroll 4
        for (int s = s0; s < s1; ++s) {
            float4 v = base[(size_t)s * (HH / 4) + t];
            acc.x += v.x; acc.y += v.y; acc.z += v.z; acc.w += v.w;
        }
        const float inv = 1.0f / fmaxf((float)(s1 - s0), 1.0f);
        acc.x *= inv; acc.y *= inv; acc.z *= inv; acc.w *= inv;
        fout[(HH / 4) + t] = acc;
    }

    // obj mean
    {
        const int s0 = obj[2 * b], s1 = obj[2 * b + 1];
        float4 acc = make_float4(0.f, 0.f, 0.f, 0.f);
        #pragma unroll 4
        for (int s = s0; s < s1; ++s) {
            float4 v = base[(size_t)s * (HH / 4) + t];
            acc.x += v.x; acc.y += v.y; acc.z += v.z; acc.w += v.w;
        }
        const float inv = 1.0f / fmaxf((float)(s1 - s0), 1.0f);
        acc.x *= inv; acc.y *= inv; acc.z *= inv; acc.w *= inv;
        fout[2 * (HH / 4) + t] = acc;
    }
}

// ---------------- Kernel 2: GEMM partials -----------------------------------
// part[p][j][b] = sum_{k in chunk p} feats[b][k] * W[j][k]
// grid 512 = (32 j-groups) x (16 k-parts), 256 threads = 4 waves.
// lane = b (all 64 batches); wave handles RJ=8 j-columns; W rows are
// wave-uniform -> scalar (SMEM) loads; feats chunk staged once in LDS.
__global__ __launch_bounds__(256) void gemm_kernel(
    const float* __restrict__ feats,  // (B,3H)
    const float* __restrict__ W,      // (H,3H) row-major
    float*       __restrict__ part)   // (KSPLIT, H, B)
{
    __shared__ float lds[BB][LDS_PAD];

    const int bid   = blockIdx.x;
    const int kpart = bid & 15;
    const int jg    = bid >> 4;             // 0..31
    const int kbase = kpart * KCHUNK;
    const int tid   = threadIdx.x;

    // stage feats[:, kbase:kbase+192] -> lds[b][k]
    {
        const int b = tid >> 2, q = tid & 3;
        const float4* src = (const float4*)(feats + (size_t)b * K3 + kbase);
        #pragma unroll
        for (int i = 0; i < 12; ++i) {
            const int f4i = i * 4 + q;              // interleaved for coalescing
            float4 v = src[f4i];
            *(float4*)&lds[b][f4i * 4] = v;
        }
    }
    __syncthreads();

    const int w    = __builtin_amdgcn_readfirstlane(tid >> 6);  // provably uniform
    const int lane = tid & 63;                                  // = batch b
    const int j0   = jg * JTILE + w * RJ;

    float acc[RJ];
    #pragma unroll
    for (int jj = 0; jj < RJ; ++jj) acc[jj] = 0.f;

    const float* wp = W + (size_t)j0 * K3 + kbase;  // uniform -> s_load

    #pragma unroll 4
    for (int kk = 0; kk < KCHUNK; kk += 4) {
        const float4 f = *(const float4*)&lds[lane][kk];   // ds_read_b128, bank-balanced
        #pragma unroll
        for (int jj = 0; jj < RJ; ++jj) {
            const float4 wv = *(const float4*)(wp + (size_t)jj * K3 + kk);
            acc[jj] = fmaf(f.x, wv.x, acc[jj]);
            acc[jj] = fmaf(f.y, wv.y, acc[jj]);
            acc[jj] = fmaf(f.z, wv.z, acc[jj]);
            acc[jj] = fmaf(f.w, wv.w, acc[jj]);
        }
    }

    float* pp = part + ((size_t)kpart * HH + j0) * BB + lane;
    #pragma unroll
    for (int jj = 0; jj < RJ; ++jj)
        pp[jj * BB] = acc[jj];                      // coalesced over lanes
}

// ---------------- Kernel 3: reduce k-parts + bias + tanh --------------------
// grid 256, 256 threads: block covers 4 j-columns x 64 b.
__global__ __launch_bounds__(256) void reduce_kernel(
    const float* __restrict__ part,   // (KSPLIT, H, B)
    const float* __restrict__ bias,   // (H)
    float*       __restrict__ out)    // (B,H)
{
    const int t = threadIdx.x;
    const int j = blockIdx.x * 4 + (t >> 6);
    const int b = t & 63;
    float s = 0.f;
    #pragma unroll
    for (int p = 0; p < KSPLIT; ++p)
        s += part[((size_t)p * HH + j) * BB + b];   // coalesced over lanes
    out[(size_t)b * HH + j] = tanhf(s + bias[j]);
}

extern "C" void kernel_launch(void* const* d_in, const int* in_sizes, int n_in,
                              void* d_out, int out_size, void* d_ws, size_t ws_size,
                              hipStream_t stream) {
    const float* hs   = (const float*)d_in[0];  // (B,S,H) fp32
    const int*   subj = (const int*)d_in[1];    // (B,2) int32
    const int*   obj  = (const int*)d_in[2];    // (B,2) int32
    const float* W    = (const float*)d_in[3];  // (H,3H) fp32
    const float* bias = (const float*)d_in[4];  // (H) fp32
    float*       out  = (float*)d_out;          // (B,H) fp32

    float* feats = (float*)d_ws;                            // 786,432 B
    float* part  = (float*)((char*)d_ws + (1 << 20));       // 4 MB at +1 MB

    feats_kernel<<<BB * 4, 64, 0, stream>>>(hs, subj, obj, feats);
    gemm_kernel<<<32 * KSPLIT, 256, 0, stream>>>(feats, W, part);
    reduce_kernel<<<HH / 4, 256, 0, stream>>>(part, bias, out);
}

// Round 3
// 26.438 us; speedup vs baseline: 2.6395x; 1.3701x over previous
//
#include <hip/hip_runtime.h>
#include <math.h>

// B=64, S=512, H=1024
#define BB 64
#define SS 512
#define HH 1024
#define K3 3072
#define KSPLIT 16
#define KCHUNK 192          // K3 / KSPLIT
#define JTILE 32            // j-columns per block (8 waves x RJ)
#define RJ 4                // j-columns per wave
#define LDS_PAD 196         // feats row stride in floats (16B-aligned, 2-way banks = free)

// ---------------- Kernel 1: feats[b, 0:3H] = [first, subj-mean, obj-mean] ----
// grid 192 x 256 threads.
//   bid < 128 : mean job (b = bid>>1, feat = bid&1). 4 waves split the s-range
//               (wave w takes rows s0+w, s0+w+4, ...; serial depth <= 8),
//               LDS reduce across waves.
//   bid >= 128: first-token copy for batch (bid-128); 256 threads x 1 float4.
__global__ __launch_bounds__(256) void feats_kernel(
    const float* __restrict__ hs,     // (B,S,H)
    const int*   __restrict__ subj,   // (B,2)
    const int*   __restrict__ obj,    // (B,2)
    float*       __restrict__ feats)  // (B,3H)
{
    const int bid = blockIdx.x;
    const int tid = threadIdx.x;

    if (bid >= 128) {                 // first-token copy
        const int b = bid - 128;
        const float4* src = (const float4*)(hs + (size_t)b * SS * HH);
        float4* dst = (float4*)(feats + (size_t)b * K3);
        dst[tid] = src[tid];
        return;
    }

    __shared__ float4 lds[4 * 256];   // 4 wave-partials of H floats (16 KB)

    const int b    = bid >> 1;
    const int feat = bid & 1;
    const int* rng = feat ? obj : subj;
    const int s0 = rng[2 * b], s1 = rng[2 * b + 1];

    const int w    = tid >> 6;        // wave 0..3
    const int lane = tid & 63;

    const float4* base = (const float4*)(hs + (size_t)b * SS * HH);

    float4 acc[4];                    // q = 0..3 -> float4 index q*64+lane
    #pragma unroll
    for (int q = 0; q < 4; ++q) acc[q] = make_float4(0.f, 0.f, 0.f, 0.f);

    for (int s = s0 + w; s < s1; s += 4) {
        const float4* row = base + (size_t)s * (HH / 4);
        #pragma unroll
        for (int q = 0; q < 4; ++q) {
            float4 v = row[q * 64 + lane];
            acc[q].x += v.x; acc[q].y += v.y; acc[q].z += v.z; acc[q].w += v.w;
        }
    }

    #pragma unroll
    for (int q = 0; q < 4; ++q)
        lds[w * 256 + q * 64 + lane] = acc[q];
    __syncthreads();

    // thread t sums the 4 wave-partials for float4 index t
    float4 s = lds[tid];
    #pragma unroll
    for (int p = 1; p < 4; ++p) {
        float4 v = lds[p * 256 + tid];
        s.x += v.x; s.y += v.y; s.z += v.z; s.w += v.w;
    }
    const float inv = 1.0f / fmaxf((float)(s1 - s0), 1.0f);
    s.x *= inv; s.y *= inv; s.z *= inv; s.w *= inv;
    ((float4*)(feats + (size_t)b * K3 + (1 + feat) * HH))[tid] = s;
}

// ---------------- Kernel 2: GEMM partials -----------------------------------
// part[p][j][b] = sum_{k in chunk p} feats[b][k] * W[j][k]
// grid 512 = (32 j-groups) x (16 k-parts), 512 threads = 8 waves.
// lane = b; wave handles RJ=4 j-columns (wave-uniform W rows -> s_load);
// feats chunk staged once in LDS per block (shared by 8 waves).
// 4096 waves total = 4 waves/SIMD.
__global__ __launch_bounds__(512) void gemm_kernel(
    const float* __restrict__ feats,  // (B,3H)
    const float* __restrict__ W,      // (H,3H) row-major
    float*       __restrict__ part)   // (KSPLIT, H, B)
{
    __shared__ float lds[BB][LDS_PAD];    // 49 KB

    const int bid   = blockIdx.x;
    const int kpart = bid & 15;
    const int jg    = bid >> 4;           // 0..31
    const int kbase = kpart * KCHUNK;
    const int tid   = threadIdx.x;

    // stage feats[:, kbase:kbase+192] -> lds[b][k]; 8 threads per row, 6 f4 each
    {
        const int b = tid >> 3, q = tid & 7;
        const float4* src = (const float4*)(feats + (size_t)b * K3 + kbase);
        #pragma unroll
        for (int i = 0; i < 6; ++i) {
            const int f4i = i * 8 + q;
            *(float4*)&lds[b][f4i * 4] = src[f4i];
        }
    }
    __syncthreads();

    const int w    = __builtin_amdgcn_readfirstlane(tid >> 6);  // 0..7, uniform
    const int lane = tid & 63;                                  // = batch b
    const int j0   = jg * JTILE + w * RJ;

    float acc[RJ];
    #pragma unroll
    for (int jj = 0; jj < RJ; ++jj) acc[jj] = 0.f;

    const float* wp = W + (size_t)j0 * K3 + kbase;  // uniform -> s_load

    #pragma unroll 4
    for (int kk = 0; kk < KCHUNK; kk += 4) {
        const float4 f = *(const float4*)&lds[lane][kk];
        #pragma unroll
        for (int jj = 0; jj < RJ; ++jj) {
            const float4 wv = *(const float4*)(wp + (size_t)jj * K3 + kk);
            acc[jj] = fmaf(f.x, wv.x, acc[jj]);
            acc[jj] = fmaf(f.y, wv.y, acc[jj]);
            acc[jj] = fmaf(f.z, wv.z, acc[jj]);
            acc[jj] = fmaf(f.w, wv.w, acc[jj]);
        }
    }

    float* pp = part + ((size_t)kpart * HH + j0) * BB + lane;
    #pragma unroll
    for (int jj = 0; jj < RJ; ++jj)
        pp[jj * BB] = acc[jj];                      // coalesced over lanes
}

// ---------------- Kernel 3: reduce k-parts + bias + tanh --------------------
// grid 256 x 256: block covers 4 j-columns x 64 b.
__global__ __launch_bounds__(256) void reduce_kernel(
    const float* __restrict__ part,   // (KSPLIT, H, B)
    const float* __restrict__ bias,   // (H)
    float*       __restrict__ out)    // (B,H)
{
    const int t = threadIdx.x;
    const int j = blockIdx.x * 4 + (t >> 6);
    const int b = t & 63;
    float s = 0.f;
    #pragma unroll
    for (int p = 0; p < KSPLIT; ++p)
        s += part[((size_t)p * HH + j) * BB + b];   // coalesced over lanes
    out[(size_t)b * HH + j] = tanhf(s + bias[j]);
}

extern "C" void kernel_launch(void* const* d_in, const int* in_sizes, int n_in,
                              void* d_out, int out_size, void* d_ws, size_t ws_size,
                              hipStream_t stream) {
    const float* hs   = (const float*)d_in[0];  // (B,S,H) fp32
    const int*   subj = (const int*)d_in[1];    // (B,2) int32
    const int*   obj  = (const int*)d_in[2];    // (B,2) int32
    const float* W    = (const float*)d_in[3];  // (H,3H) fp32
    const float* bias = (const float*)d_in[4];  // (H) fp32
    float*       out  = (float*)d_out;          // (B,H) fp32

    float* feats = (float*)d_ws;                            // 768 KB
    float* part  = (float*)((char*)d_ws + (1 << 20));       // 4 MB at +1 MB

    feats_kernel<<<192, 256, 0, stream>>>(hs, subj, obj, feats);
    gemm_kernel<<<JTILE * KSPLIT, 512, 0, stream>>>(feats, W, part);
    reduce_kernel<<<HH / 4, 256, 0, stream>>>(part, bias, out);
}